// Round 1
// baseline (467.359 us; speedup 1.0000x reference)
//
#include <hip/hip_runtime.h>
#include <stdint.h>

typedef __attribute__((ext_vector_type(8))) short bf16x8;
typedef __attribute__((ext_vector_type(4))) float f32x4;

#define MFMA16(a, b, c) __builtin_amdgcn_mfma_f32_16x16x32_bf16(a, b, c, 0, 0, 0)

// Problem constants
#define BB 4
#define TT 2048
#define CC 576
#define NH 9
#define NKV 3
#define HD 64
#define MM (BB * TT)          // 8192
#define NQKV 960              // 576 + 192 + 192

__device__ __forceinline__ unsigned short f2bf(float f) {
  union { float f; uint32_t u; } v; v.f = f;
  uint32_t u = v.u;
  uint32_t r = (u + 0x7fffu + ((u >> 16) & 1u)) >> 16;
  return (unsigned short)r;
}

// ---------------------------------------------------------------------------
// Prep: f32 -> bf16 conversions + RoPE cos/sin table (double precision)
// ---------------------------------------------------------------------------
__global__ __launch_bounds__(256) void prep_kernel(
    const float* __restrict__ x, const float* __restrict__ wq,
    const float* __restrict__ wk, const float* __restrict__ wv,
    const float* __restrict__ wo,
    unsigned short* __restrict__ xh, unsigned short* __restrict__ wqkv,
    unsigned short* __restrict__ woh, float* __restrict__ tc,
    float* __restrict__ ts) {
  const int NX = MM * CC;          // 4718592
  const int NW = NQKV * CC;        // 552960
  const int NO = CC * CC;          // 331776
  const int NT = TT * 32;          // 65536
  const int total = NX + NW + NO + NT;
  for (int i = blockIdx.x * blockDim.x + threadIdx.x; i < total;
       i += gridDim.x * blockDim.x) {
    if (i < NX) {
      xh[i] = f2bf(x[i]);
    } else if (i < NX + NW) {
      int j = i - NX;
      int n = j / CC;
      float w = (n < 576) ? wq[j] : (n < 768) ? wk[j - 576 * CC] : wv[j - 768 * CC];
      wqkv[j] = f2bf(w);
    } else if (i < NX + NW + NO) {
      int j = i - NX - NW;
      woh[j] = f2bf(wo[j]);
    } else {
      int j = i - NX - NW - NO;
      int t = j >> 5, pi = j & 31;
      double invf = pow(100000.0, -(double)(2 * pi) / 64.0);
      double ang = (double)t * invf;
      tc[j] = (float)cos(ang);
      ts[j] = (float)sin(ang);
    }
  }
}

// ---------------------------------------------------------------------------
// GEMM1: [8192 x 576] @ [960 x 576]^T -> q/k (RoPE'd) and v (transposed)
// block = 256 threads (4 waves), tile 64x64, wave tile 32x32
// ---------------------------------------------------------------------------
__global__ __launch_bounds__(256) void gemm_qkv(
    const unsigned short* __restrict__ xh, const unsigned short* __restrict__ wqkv,
    const float* __restrict__ tc, const float* __restrict__ ts,
    unsigned short* __restrict__ qb, unsigned short* __restrict__ kbuf,
    unsigned short* __restrict__ vT) {
  const int l = threadIdx.x & 63, w = threadIdx.x >> 6;
  const int lr = l & 15, lg = l >> 4;
  const int wr = w >> 1, wc = w & 1;
  const int bm = blockIdx.y * 64, bn = blockIdx.x * 64;
  const int r0 = bm + wr * 32, c0 = bn + wc * 32;

  f32x4 acc[2][2] = {};
#pragma unroll 2
  for (int k0 = 0; k0 < CC; k0 += 32) {
    bf16x8 a[2], b[2];
#pragma unroll
    for (int i = 0; i < 2; ++i) {
      a[i] = *(const bf16x8*)(xh + (size_t)(r0 + i * 16 + lr) * CC + k0 + lg * 8);
      b[i] = *(const bf16x8*)(wqkv + (size_t)(c0 + i * 16 + lr) * CC + k0 + lg * 8);
    }
#pragma unroll
    for (int mi = 0; mi < 2; ++mi)
#pragma unroll
      for (int ni = 0; ni < 2; ++ni)
        acc[mi][ni] = MFMA16(a[mi], b[ni], acc[mi][ni]);
  }

#pragma unroll
  for (int mi = 0; mi < 2; ++mi) {
#pragma unroll
    for (int ni = 0; ni < 2; ++ni) {
      const int col = c0 + ni * 16 + lr;
#pragma unroll
      for (int r = 0; r < 4; ++r) {
        const int m = r0 + mi * 16 + lg * 4 + r;
        float v = acc[mi][ni][r];
        float partner = __shfl_xor(v, 1);
        const int bi = m >> 11, t = m & 2047;
        const int d = col & 63;
        if (col < 768) {  // RoPE for q and k
          const int pi = d >> 1;
          const float c = tc[t * 32 + pi], s = ts[t * 32 + pi];
          v = (d & 1) ? (partner * s + v * c) : (v * c - partner * s);
        }
        if (col < 576) {
          const int h = col >> 6;
          qb[(((size_t)bi * NH + h) * TT + t) * HD + d] = f2bf(v);
        } else if (col < 768) {
          const int h = (col - 576) >> 6;
          kbuf[(((size_t)bi * NKV + h) * TT + t) * HD + d] = f2bf(v);
        } else {
          const int h = (col - 768) >> 6;
          vT[(((size_t)bi * NKV + h) * HD + d) * TT + t] = f2bf(v);
        }
      }
    }
  }
}

// ---------------------------------------------------------------------------
// Flash attention: causal, GQA (3 q-heads per kv-head)
// grid = (qt=32, h=9, b=4), block = 256 (4 waves), Q-tile 64 rows (16/wave),
// KV tile 64. Online softmax; P transposed through LDS.
// ---------------------------------------------------------------------------
__global__ __launch_bounds__(256) void attn_kernel(
    const unsigned short* __restrict__ qb, const unsigned short* __restrict__ kbuf,
    const unsigned short* __restrict__ vT, unsigned short* __restrict__ yb) {
  const int qt = blockIdx.x, h = blockIdx.y, b = blockIdx.z;
  const int l = threadIdx.x & 63, w = threadIdx.x >> 6;
  const int lr = l & 15, lg = l >> 4;
  const int kvh = h / 3;
  const int q0 = qt * 64;
  const int rowbase = q0 + w * 16;

  const unsigned short* qptr = qb + (((size_t)b * NH + h) * TT) * HD;
  const unsigned short* kptr = kbuf + (((size_t)b * NKV + kvh) * TT) * HD;
  const unsigned short* vptr = vT + (((size_t)b * NKV + kvh) * HD) * TT;

  __shared__ unsigned short plds[4][16][80];  // padded: row stride 160B

  bf16x8 aq[2];
#pragma unroll
  for (int kk = 0; kk < 2; ++kk)
    aq[kk] = *(const bf16x8*)(qptr + (size_t)(rowbase + lr) * HD + kk * 32 + lg * 8);

  float mi[4], li[4];
  f32x4 o[4] = {};
#pragma unroll
  for (int r = 0; r < 4; ++r) { mi[r] = -1e30f; li[r] = 0.f; }

  const int ntiles = qt + 1;
  for (int jt = 0; jt < ntiles; ++jt) {
    const int j0 = jt * 64;
    f32x4 s[4];
#pragma unroll
    for (int ct = 0; ct < 4; ++ct) {
      f32x4 acc = {};
#pragma unroll
      for (int kk = 0; kk < 2; ++kk) {
        bf16x8 bk = *(const bf16x8*)(kptr + (size_t)(j0 + ct * 16 + lr) * HD + kk * 32 + lg * 8);
        acc = MFMA16(aq[kk], bk, acc);
      }
#pragma unroll
      for (int r = 0; r < 4; ++r) s[ct][r] = acc[r] * 0.125f;
    }
    if (jt == ntiles - 1) {  // diagonal tile: causal mask
#pragma unroll
      for (int ct = 0; ct < 4; ++ct)
#pragma unroll
        for (int r = 0; r < 4; ++r) {
          const int row = rowbase + lg * 4 + r, colg = j0 + ct * 16 + lr;
          if (colg > row) s[ct][r] = -1e30f;
        }
    }
    // online softmax per row (each lane owns 4 rows)
#pragma unroll
    for (int r = 0; r < 4; ++r) {
      float pm = fmaxf(fmaxf(s[0][r], s[1][r]), fmaxf(s[2][r], s[3][r]));
#pragma unroll
      for (int off = 1; off < 16; off <<= 1) pm = fmaxf(pm, __shfl_xor(pm, off));
      const float mn = fmaxf(mi[r], pm);
      const float alpha = __expf(mi[r] - mn);
      mi[r] = mn;
      li[r] *= alpha;
#pragma unroll
      for (int dt = 0; dt < 4; ++dt) o[dt][r] *= alpha;
      float psum = 0.f;
#pragma unroll
      for (int ct = 0; ct < 4; ++ct) {
        const float p = __expf(s[ct][r] - mn);
        s[ct][r] = p;
        psum += p;
      }
#pragma unroll
      for (int off = 1; off < 16; off <<= 1) psum += __shfl_xor(psum, off);
      li[r] += psum;
    }
    // P (C-layout) -> LDS -> A-layout fragments
#pragma unroll
    for (int ct = 0; ct < 4; ++ct)
#pragma unroll
      for (int r = 0; r < 4; ++r)
        plds[w][lg * 4 + r][ct * 16 + lr] = f2bf(s[ct][r]);
    // PV
#pragma unroll
    for (int kk = 0; kk < 2; ++kk) {
      bf16x8 ap = *(const bf16x8*)(&plds[w][lr][kk * 32 + lg * 8]);
#pragma unroll
      for (int dt = 0; dt < 4; ++dt) {
        bf16x8 bv = *(const bf16x8*)(vptr + (size_t)(dt * 16 + lr) * TT + j0 + kk * 32 + lg * 8);
        o[dt] = MFMA16(ap, bv, o[dt]);
      }
    }
  }

  // epilogue: normalize, write y as bf16 [b][t][h*64+d]
#pragma unroll
  for (int r = 0; r < 4; ++r) {
    const float inv = 1.f / li[r];
    const int t = rowbase + lg * 4 + r;
#pragma unroll
    for (int dt = 0; dt < 4; ++dt)
      yb[((size_t)b * TT + t) * CC + h * HD + dt * 16 + lr] = f2bf(o[dt][r] * inv);
  }
}

// ---------------------------------------------------------------------------
// GEMM2: y [8192 x 576] @ wo [576 x 576]^T -> out f32
// ---------------------------------------------------------------------------
__global__ __launch_bounds__(256) void gemm_out(
    const unsigned short* __restrict__ yb, const unsigned short* __restrict__ woh,
    float* __restrict__ out) {
  const int l = threadIdx.x & 63, w = threadIdx.x >> 6;
  const int lr = l & 15, lg = l >> 4;
  const int wr = w >> 1, wc = w & 1;
  const int bm = blockIdx.y * 64, bn = blockIdx.x * 64;
  const int r0 = bm + wr * 32, c0 = bn + wc * 32;

  f32x4 acc[2][2] = {};
#pragma unroll 2
  for (int k0 = 0; k0 < CC; k0 += 32) {
    bf16x8 a[2], b[2];
#pragma unroll
    for (int i = 0; i < 2; ++i) {
      a[i] = *(const bf16x8*)(yb + (size_t)(r0 + i * 16 + lr) * CC + k0 + lg * 8);
      b[i] = *(const bf16x8*)(woh + (size_t)(c0 + i * 16 + lr) * CC + k0 + lg * 8);
    }
#pragma unroll
    for (int mi = 0; mi < 2; ++mi)
#pragma unroll
      for (int ni = 0; ni < 2; ++ni)
        acc[mi][ni] = MFMA16(a[mi], b[ni], acc[mi][ni]);
  }
#pragma unroll
  for (int mi = 0; mi < 2; ++mi)
#pragma unroll
    for (int ni = 0; ni < 2; ++ni) {
      const int col = c0 + ni * 16 + lr;
#pragma unroll
      for (int r = 0; r < 4; ++r) {
        const int m = r0 + mi * 16 + lg * 4 + r;
        out[(size_t)m * CC + col] = acc[mi][ni][r];
      }
    }
}

// ---------------------------------------------------------------------------
extern "C" void kernel_launch(void* const* d_in, const int* in_sizes, int n_in,
                              void* d_out, int out_size, void* d_ws, size_t ws_size,
                              hipStream_t stream) {
  const float* x = (const float*)d_in[0];
  const float* wq = (const float*)d_in[1];
  const float* wk = (const float*)d_in[2];
  const float* wv = (const float*)d_in[3];
  const float* wo = (const float*)d_in[4];
  float* out = (float*)d_out;

  char* ws = (char*)d_ws;
  unsigned short* xh = (unsigned short*)ws;    ws += (size_t)MM * CC * 2;        // 9.4 MB
  unsigned short* wqkv = (unsigned short*)ws;  ws += (size_t)NQKV * CC * 2;      // 1.1 MB
  unsigned short* woh = (unsigned short*)ws;   ws += (size_t)CC * CC * 2;        // 0.66 MB
  float* tc = (float*)ws;                      ws += (size_t)TT * 32 * 4;        // 256 KB
  float* tsn = (float*)ws;                     ws += (size_t)TT * 32 * 4;        // 256 KB
  unsigned short* qb = (unsigned short*)ws;    ws += (size_t)BB * NH * TT * HD * 2;   // 9.4 MB
  unsigned short* kbuf = (unsigned short*)ws;  ws += (size_t)BB * NKV * TT * HD * 2;  // 3.1 MB
  unsigned short* vT = (unsigned short*)ws;    ws += (size_t)BB * NKV * HD * TT * 2;  // 3.1 MB
  unsigned short* yb = (unsigned short*)ws;    ws += (size_t)MM * CC * 2;        // 9.4 MB

  prep_kernel<<<dim3(2048), dim3(256), 0, stream>>>(x, wq, wk, wv, wo, xh, wqkv, woh, tc, tsn);
  gemm_qkv<<<dim3(NQKV / 64, MM / 64), dim3(256), 0, stream>>>(xh, wqkv, tc, tsn, qb, kbuf, vT);
  attn_kernel<<<dim3(TT / 64, NH, BB), dim3(256), 0, stream>>>(qb, kbuf, vT, yb);
  gemm_out<<<dim3(CC / 64, MM / 64), dim3(256), 0, stream>>>(yb, woh, out);
}

// Round 2
// 240.236 us; speedup vs baseline: 1.9454x; 1.9454x over previous
//
#include <hip/hip_runtime.h>
#include <stdint.h>

typedef __attribute__((ext_vector_type(8))) short bf16x8;
typedef __attribute__((ext_vector_type(4))) float f32x4;

#define MFMA16(a, b, c) __builtin_amdgcn_mfma_f32_16x16x32_bf16(a, b, c, 0, 0, 0)

// Problem constants
#define BB 4
#define TT 2048
#define CC 576
#define NH 9
#define NKV 3
#define HD 64
#define MM (BB * TT)          // 8192
#define NQKV 960              // 576 + 192 + 192

__device__ __forceinline__ unsigned short f2bf(float f) {
  union { float f; uint32_t u; } v; v.f = f;
  uint32_t u = v.u;
  uint32_t r = (u + 0x7fffu + ((u >> 16) & 1u)) >> 16;
  return (unsigned short)r;
}

__device__ __forceinline__ void gl16(const void* g, void* l) {
  __builtin_amdgcn_global_load_lds(
      (const __attribute__((address_space(1))) unsigned int*)g,
      (__attribute__((address_space(3))) unsigned int*)l, 16, 0, 0);
}

// ---------------------------------------------------------------------------
// Prep: f32 -> bf16 conversions + RoPE cos/sin table (double precision)
// ---------------------------------------------------------------------------
__global__ __launch_bounds__(256) void prep_kernel(
    const float* __restrict__ x, const float* __restrict__ wq,
    const float* __restrict__ wk, const float* __restrict__ wv,
    const float* __restrict__ wo,
    unsigned short* __restrict__ xh, unsigned short* __restrict__ wqkv,
    unsigned short* __restrict__ woh, float* __restrict__ tc,
    float* __restrict__ ts) {
  const int NX = MM * CC;          // 4718592
  const int NW = NQKV * CC;        // 552960
  const int NO = CC * CC;          // 331776
  const int NT = TT * 32;          // 65536
  const int total = NX + NW + NO + NT;
  for (int i = blockIdx.x * blockDim.x + threadIdx.x; i < total;
       i += gridDim.x * blockDim.x) {
    if (i < NX) {
      xh[i] = f2bf(x[i]);
    } else if (i < NX + NW) {
      int j = i - NX;
      int n = j / CC;
      float w = (n < 576) ? wq[j] : (n < 768) ? wk[j - 576 * CC] : wv[j - 768 * CC];
      wqkv[j] = f2bf(w);
    } else if (i < NX + NW + NO) {
      int j = i - NX - NW;
      woh[j] = f2bf(wo[j]);
    } else {
      int j = i - NX - NW - NO;
      int t = j >> 5, pi = j & 31;
      double invf = pow(100000.0, -(double)(2 * pi) / 64.0);
      double ang = (double)t * invf;
      tc[j] = (float)cos(ang);
      ts[j] = (float)sin(ang);
    }
  }
}

// ---------------------------------------------------------------------------
// GEMM1: [8192 x 576] @ [960 x 576]^T -> q (RoPE'd, [b][h][t][d]),
// K (RoPE'd, staged swizzled tiles), V (transposed, staged swizzled tiles)
// Staged layout: per (head=b*NKV+kvh, jt) tile of 64x64 bf16 (8KB):
//   K: elem [r][d] stored at r*64 + (d ^ ((r&7)<<3))
//   V: elem [d][tc] stored at d*64 + (tc ^ ((d&7)<<3))
// so that a LINEAR global_load_lds copy produces an XOR-swizzled LDS image
// (conflict-free ds_read_b128 in the attention kernel).
// ---------------------------------------------------------------------------
__global__ __launch_bounds__(256) void gemm_qkv(
    const unsigned short* __restrict__ xh, const unsigned short* __restrict__ wqkv,
    const float* __restrict__ tc, const float* __restrict__ ts,
    unsigned short* __restrict__ qb, unsigned short* __restrict__ kst,
    unsigned short* __restrict__ vst) {
  const int l = threadIdx.x & 63, w = threadIdx.x >> 6;
  const int lr = l & 15, lg = l >> 4;
  const int wr = w >> 1, wc = w & 1;
  const int bm = blockIdx.y * 64, bn = blockIdx.x * 64;
  const int r0 = bm + wr * 32, c0 = bn + wc * 32;

  f32x4 acc[2][2] = {};
#pragma unroll 2
  for (int k0 = 0; k0 < CC; k0 += 32) {
    bf16x8 a[2], b[2];
#pragma unroll
    for (int i = 0; i < 2; ++i) {
      a[i] = *(const bf16x8*)(xh + (size_t)(r0 + i * 16 + lr) * CC + k0 + lg * 8);
      b[i] = *(const bf16x8*)(wqkv + (size_t)(c0 + i * 16 + lr) * CC + k0 + lg * 8);
    }
#pragma unroll
    for (int mi = 0; mi < 2; ++mi)
#pragma unroll
      for (int ni = 0; ni < 2; ++ni)
        acc[mi][ni] = MFMA16(a[mi], b[ni], acc[mi][ni]);
  }

#pragma unroll
  for (int mi = 0; mi < 2; ++mi) {
#pragma unroll
    for (int ni = 0; ni < 2; ++ni) {
      const int col = c0 + ni * 16 + lr;
#pragma unroll
      for (int r = 0; r < 4; ++r) {
        const int m = r0 + mi * 16 + lg * 4 + r;
        float v = acc[mi][ni][r];
        float partner = __shfl_xor(v, 1);
        const int bi = m >> 11, t = m & 2047;
        const int d = col & 63;
        if (col < 768) {  // RoPE for q and k
          const int pi = d >> 1;
          const float c = tc[t * 32 + pi], s = ts[t * 32 + pi];
          v = (d & 1) ? (partner * s + v * c) : (v * c - partner * s);
        }
        if (col < 576) {
          const int h = col >> 6;
          qb[(((size_t)bi * NH + h) * TT + t) * HD + d] = f2bf(v);
        } else if (col < 768) {
          const int h = (col - 576) >> 6;
          const size_t head = (size_t)bi * NKV + h;
          kst[((head * 32 + (t >> 6)) * 64 + (t & 63)) * 64 + (d ^ ((t & 7) << 3))] = f2bf(v);
        } else {
          const int h = (col - 768) >> 6;
          const size_t head = (size_t)bi * NKV + h;
          vst[((head * 32 + (t >> 6)) * 64 + d) * 64 + ((t & 63) ^ ((d & 7) << 3))] = f2bf(v);
        }
      }
    }
  }
}

// ---------------------------------------------------------------------------
// Flash attention: causal, GQA. grid = (16 pairs, 9, 4), block = 256 (4 waves).
// Block `pair` processes q-tiles {31-pair, pair} (64 rows each) -> exactly 33
// tile-iterations per block (load-balanced). K/V 64x64 tiles double-buffered
// in LDS via global_load_lds (swizzled image), 2-phase schedule.
// ---------------------------------------------------------------------------
__global__ __launch_bounds__(256) void attn_kernel(
    const unsigned short* __restrict__ qb, const unsigned short* __restrict__ kst,
    const unsigned short* __restrict__ vst, unsigned short* __restrict__ yb) {
  const int pair = blockIdx.x, h = blockIdx.y, b = blockIdx.z;
  const int l = threadIdx.x & 63, w = threadIdx.x >> 6;
  const int lr = l & 15, lg = l >> 4;
  const int kvh = h / 3;
  const size_t head = (size_t)b * NKV + kvh;

  const int qtA = 31 - pair, qtB = pair;
  const int ntA = qtA + 1;
  const int nt = ntA + qtB + 1;   // 33 always

  __shared__ unsigned short kls[2][4096];
  __shared__ unsigned short vls[2][4096];
  __shared__ unsigned short plds[4][16][72];

  const unsigned short* qptr = qb + ((size_t)b * NH + h) * TT * HD;

  bf16x8 aqA[2], aqB[2];
#pragma unroll
  for (int kk = 0; kk < 2; ++kk) {
    aqA[kk] = *(const bf16x8*)(qptr + (size_t)(qtA * 64 + w * 16 + lr) * HD + kk * 32 + lg * 8);
    aqB[kk] = *(const bf16x8*)(qptr + (size_t)(qtB * 64 + w * 16 + lr) * HD + kk * 32 + lg * 8);
  }

  const char* kgb = (const char*)(kst + head * 32 * 4096);
  const char* vgb = (const char*)(vst + head * 32 * 4096);
  const int so = w * 1024 + l * 16;  // per-lane source byte offset in 4KB half
  const int lo = w * 1024;           // wave-uniform LDS byte offset

  float mi[4], li[4];
  f32x4 o[4];
#pragma unroll
  for (int r = 0; r < 4; ++r) { mi[r] = -1e30f; li[r] = 0.f; }
#pragma unroll
  for (int dt = 0; dt < 4; ++dt) o[dt] = f32x4{0.f, 0.f, 0.f, 0.f};

  // stage tile 0 (segment A, jt=0) into buffer 0
  {
    char* kl = (char*)&kls[0][0];
    char* vl = (char*)&vls[0][0];
    gl16(kgb + so, kl + lo);
    gl16(kgb + 4096 + so, kl + 4096 + lo);
    gl16(vgb + so, vl + lo);
    gl16(vgb + 4096 + so, vl + 4096 + lo);
  }
  __syncthreads();

  const float SC = 0.125f * 1.44269504088896f;  // scale * log2(e)
  const int sw = (lr & 7) << 4;
  int cur = 0;

  for (int it = 0; it < nt; ++it) {
    const bool segA = it < ntA;
    const int jt = segA ? it : it - ntA;
    const int qt = segA ? qtA : qtB;

    if (it + 1 < nt) {  // stage next tile into other buffer
      const int njt = (it + 1 < ntA) ? it + 1 : it + 1 - ntA;
      const size_t tb = (size_t)njt * 8192;
      char* kl = (char*)&kls[cur ^ 1][0];
      char* vl = (char*)&vls[cur ^ 1][0];
      gl16(kgb + tb + so, kl + lo);
      gl16(kgb + tb + 4096 + so, kl + 4096 + lo);
      gl16(vgb + tb + so, vl + lo);
      gl16(vgb + tb + 4096 + so, vl + 4096 + lo);
    }

    const char* kb = (const char*)&kls[cur][0];
    const char* vb = (const char*)&vls[cur][0];
    const bf16x8 aq0 = segA ? aqA[0] : aqB[0];
    const bf16x8 aq1 = segA ? aqA[1] : aqB[1];

    // QK^T from swizzled LDS
    f32x4 s[4];
#pragma unroll
    for (int ct = 0; ct < 4; ++ct) {
      const char* krow = kb + (ct * 16 + lr) * 128;
      bf16x8 bk0 = *(const bf16x8*)(krow + ((lg * 16) ^ sw));
      bf16x8 bk1 = *(const bf16x8*)(krow + ((64 + lg * 16) ^ sw));
      f32x4 acc = {};
      acc = MFMA16(aq0, bk0, acc);
      acc = MFMA16(aq1, bk1, acc);
#pragma unroll
      for (int r = 0; r < 4; ++r) s[ct][r] = acc[r] * SC;
    }

    if (jt == qt) {  // diagonal tile: causal mask
#pragma unroll
      for (int ct = 0; ct < 4; ++ct)
#pragma unroll
        for (int r = 0; r < 4; ++r)
          if (ct * 16 + lr > w * 16 + lg * 4 + r) s[ct][r] = -1e30f;
    }

    // online softmax (exp2 domain), each lane owns 4 rows across 16 lr-lanes
#pragma unroll
    for (int r = 0; r < 4; ++r) {
      float pm = fmaxf(fmaxf(s[0][r], s[1][r]), fmaxf(s[2][r], s[3][r]));
#pragma unroll
      for (int off = 1; off < 16; off <<= 1) pm = fmaxf(pm, __shfl_xor(pm, off));
      const float mn = fmaxf(mi[r], pm);
      const float al = exp2f(mi[r] - mn);
      mi[r] = mn;
      li[r] *= al;
#pragma unroll
      for (int dt = 0; dt < 4; ++dt) o[dt][r] *= al;
      float ps = 0.f;
#pragma unroll
      for (int ct = 0; ct < 4; ++ct) {
        const float p = exp2f(s[ct][r] - mn);
        s[ct][r] = p;
        ps += p;
      }
#pragma unroll
      for (int off = 1; off < 16; off <<= 1) ps += __shfl_xor(ps, off);
      li[r] += ps;
    }

    // P (C-layout) -> per-wave LDS -> A-layout fragments
#pragma unroll
    for (int ct = 0; ct < 4; ++ct)
#pragma unroll
      for (int r = 0; r < 4; ++r)
        plds[w][lg * 4 + r][ct * 16 + lr] = f2bf(s[ct][r]);

    // PV from swizzled LDS V^T
#pragma unroll
    for (int kk = 0; kk < 2; ++kk) {
      bf16x8 ap = *(const bf16x8*)(&plds[w][lr][kk * 32 + lg * 8]);
#pragma unroll
      for (int dt = 0; dt < 4; ++dt) {
        const char* vrow = vb + (dt * 16 + lr) * 128;
        bf16x8 bv = *(const bf16x8*)(vrow + ((kk * 64 + lg * 16) ^ sw));
        o[dt] = MFMA16(ap, bv, o[dt]);
      }
    }

    if (jt == qt) {  // segment done: normalize + write, reset state
#pragma unroll
      for (int r = 0; r < 4; ++r) {
        const float inv = 1.f / li[r];
        const int t = qt * 64 + w * 16 + lg * 4 + r;
#pragma unroll
        for (int dt = 0; dt < 4; ++dt)
          yb[((size_t)b * TT + t) * CC + h * HD + dt * 16 + lr] = f2bf(o[dt][r] * inv);
      }
#pragma unroll
      for (int r = 0; r < 4; ++r) { mi[r] = -1e30f; li[r] = 0.f; }
#pragma unroll
      for (int dt = 0; dt < 4; ++dt) o[dt] = f32x4{0.f, 0.f, 0.f, 0.f};
    }

    __syncthreads();  // stage complete + all waves done reading cur
    cur ^= 1;
  }
}

// ---------------------------------------------------------------------------
// GEMM2: y [8192 x 576] @ wo [576 x 576]^T -> out f32
// ---------------------------------------------------------------------------
__global__ __launch_bounds__(256) void gemm_out(
    const unsigned short* __restrict__ yb, const unsigned short* __restrict__ woh,
    float* __restrict__ out) {
  const int l = threadIdx.x & 63, w = threadIdx.x >> 6;
  const int lr = l & 15, lg = l >> 4;
  const int wr = w >> 1, wc = w & 1;
  const int bm = blockIdx.y * 64, bn = blockIdx.x * 64;
  const int r0 = bm + wr * 32, c0 = bn + wc * 32;

  f32x4 acc[2][2] = {};
#pragma unroll 2
  for (int k0 = 0; k0 < CC; k0 += 32) {
    bf16x8 a[2], b[2];
#pragma unroll
    for (int i = 0; i < 2; ++i) {
      a[i] = *(const bf16x8*)(yb + (size_t)(r0 + i * 16 + lr) * CC + k0 + lg * 8);
      b[i] = *(const bf16x8*)(woh + (size_t)(c0 + i * 16 + lr) * CC + k0 + lg * 8);
    }
#pragma unroll
    for (int mi = 0; mi < 2; ++mi)
#pragma unroll
      for (int ni = 0; ni < 2; ++ni)
        acc[mi][ni] = MFMA16(a[mi], b[ni], acc[mi][ni]);
  }
#pragma unroll
  for (int mi = 0; mi < 2; ++mi)
#pragma unroll
    for (int ni = 0; ni < 2; ++ni) {
      const int col = c0 + ni * 16 + lr;
#pragma unroll
      for (int r = 0; r < 4; ++r) {
        const int m = r0 + mi * 16 + lg * 4 + r;
        out[(size_t)m * CC + col] = acc[mi][ni][r];
      }
    }
}

// ---------------------------------------------------------------------------
extern "C" void kernel_launch(void* const* d_in, const int* in_sizes, int n_in,
                              void* d_out, int out_size, void* d_ws, size_t ws_size,
                              hipStream_t stream) {
  const float* x = (const float*)d_in[0];
  const float* wq = (const float*)d_in[1];
  const float* wk = (const float*)d_in[2];
  const float* wv = (const float*)d_in[3];
  const float* wo = (const float*)d_in[4];
  float* out = (float*)d_out;

  char* ws = (char*)d_ws;
  unsigned short* xh = (unsigned short*)ws;    ws += (size_t)MM * CC * 2;
  unsigned short* wqkv = (unsigned short*)ws;  ws += (size_t)NQKV * CC * 2;
  unsigned short* woh = (unsigned short*)ws;   ws += (size_t)CC * CC * 2;
  float* tc = (float*)ws;                      ws += (size_t)TT * 32 * 4;
  float* tsn = (float*)ws;                     ws += (size_t)TT * 32 * 4;
  unsigned short* qb = (unsigned short*)ws;    ws += (size_t)BB * NH * TT * HD * 2;
  unsigned short* kst = (unsigned short*)ws;   ws += (size_t)BB * NKV * TT * HD * 2;
  unsigned short* vst = (unsigned short*)ws;   ws += (size_t)BB * NKV * HD * TT * 2;
  unsigned short* yb = (unsigned short*)ws;    ws += (size_t)MM * CC * 2;

  prep_kernel<<<dim3(2048), dim3(256), 0, stream>>>(x, wq, wk, wv, wo, xh, wqkv, woh, tc, tsn);
  gemm_qkv<<<dim3(NQKV / 64, MM / 64), dim3(256), 0, stream>>>(xh, wqkv, tc, tsn, qb, kst, vst);
  attn_kernel<<<dim3(16, NH, BB), dim3(256), 0, stream>>>(qb, kst, vst, yb);
  gemm_out<<<dim3(CC / 64, MM / 64), dim3(256), 0, stream>>>(yb, woh, out);
}

// Round 3
// 219.045 us; speedup vs baseline: 2.1336x; 1.0967x over previous
//
#include <hip/hip_runtime.h>
#include <stdint.h>

typedef __attribute__((ext_vector_type(8))) short bf16x8;
typedef __attribute__((ext_vector_type(4))) float f32x4;
typedef __attribute__((ext_vector_type(16))) float f32x16;

#define MFMA16(a, b, c) __builtin_amdgcn_mfma_f32_16x16x32_bf16(a, b, c, 0, 0, 0)
#define MFMA32(a, b, c) __builtin_amdgcn_mfma_f32_32x32x16_bf16(a, b, c, 0, 0, 0)

// Problem constants
#define BB 4
#define TT 2048
#define CC 576
#define NH 9
#define NKV 3
#define HD 64
#define MM (BB * TT)          // 8192
#define NQKV 960              // 576 + 192 + 192

// 0.125 (1/sqrt(64)) * log2(e), folded into Q so attention runs in exp2 domain
#define QSC 0.18033688011112042f

__device__ __forceinline__ unsigned short f2bf(float f) {
  union { float f; uint32_t u; } v; v.f = f;
  uint32_t u = v.u;
  uint32_t r = (u + 0x7fffu + ((u >> 16) & 1u)) >> 16;
  return (unsigned short)r;
}

__device__ __forceinline__ void gl16(const void* g, void* l) {
  __builtin_amdgcn_global_load_lds(
      (const __attribute__((address_space(1))) unsigned int*)g,
      (__attribute__((address_space(3))) unsigned int*)l, 16, 0, 0);
}

// ---------------------------------------------------------------------------
// Prep: f32 -> bf16 conversions (vectorized) + RoPE cos/sin table
// ---------------------------------------------------------------------------
__global__ __launch_bounds__(256) void prep_kernel(
    const float* __restrict__ x, const float* __restrict__ wq,
    const float* __restrict__ wk, const float* __restrict__ wv,
    const float* __restrict__ wo,
    unsigned short* __restrict__ xh, unsigned short* __restrict__ wqkv,
    unsigned short* __restrict__ woh, float* __restrict__ tc,
    float* __restrict__ ts) {
  const int NX4 = MM * CC / 4;       // 1179648
  const int NW4 = NQKV * CC / 4;     // 138240
  const int NO4 = CC * CC / 4;       // 82944
  const int NT = TT * 32;            // 65536
  const int total = NX4 + NW4 + NO4 + NT;
  for (int i = blockIdx.x * blockDim.x + threadIdx.x; i < total;
       i += gridDim.x * blockDim.x) {
    if (i < NX4) {
      float4 v = ((const float4*)x)[i];
      ushort4 o;
      o.x = f2bf(v.x); o.y = f2bf(v.y); o.z = f2bf(v.z); o.w = f2bf(v.w);
      ((ushort4*)xh)[i] = o;
    } else if (i < NX4 + NW4) {
      int j = i - NX4;
      int n = (j * 4) / CC;
      const float* src = (n < 576) ? wq + j * 4
                       : (n < 768) ? wk + j * 4 - 576 * CC
                                   : wv + j * 4 - 768 * CC;
      float4 v = *(const float4*)src;
      ushort4 o;
      o.x = f2bf(v.x); o.y = f2bf(v.y); o.z = f2bf(v.z); o.w = f2bf(v.w);
      ((ushort4*)wqkv)[j] = o;
    } else if (i < NX4 + NW4 + NO4) {
      int j = i - NX4 - NW4;
      float4 v = ((const float4*)wo)[j];
      ushort4 o;
      o.x = f2bf(v.x); o.y = f2bf(v.y); o.z = f2bf(v.z); o.w = f2bf(v.w);
      ((ushort4*)woh)[j] = o;
    } else {
      int j = i - NX4 - NW4 - NO4;
      int t = j >> 5, pi = j & 31;
      double invf = pow(100000.0, -(double)(2 * pi) / 64.0);
      double ang = (double)t * invf;
      tc[j] = (float)cos(ang);
      ts[j] = (float)sin(ang);
    }
  }
}

// ---------------------------------------------------------------------------
// GEMM1: [8192 x 576] @ [960 x 576]^T -> q (RoPE'd + QSC-scaled, [b][h][t][d]),
// K (RoPE'd, staged swizzled 64x64 tiles), V (transposed, staged swizzled)
//   K: elem [r][d] stored at r*64 + (d ^ ((r&7)<<3))
//   V: elem [d][tc] stored at d*64 + (tc ^ ((d&7)<<3))
// ---------------------------------------------------------------------------
__global__ __launch_bounds__(256) void gemm_qkv(
    const unsigned short* __restrict__ xh, const unsigned short* __restrict__ wqkv,
    const float* __restrict__ tc, const float* __restrict__ ts,
    unsigned short* __restrict__ qb, unsigned short* __restrict__ kst,
    unsigned short* __restrict__ vst) {
  const int l = threadIdx.x & 63, w = threadIdx.x >> 6;
  const int lr = l & 15, lg = l >> 4;
  const int wr = w >> 1, wc = w & 1;
  const int bm = blockIdx.y * 64, bn = blockIdx.x * 64;
  const int r0 = bm + wr * 32, c0 = bn + wc * 32;

  f32x4 acc[2][2] = {};
#pragma unroll 2
  for (int k0 = 0; k0 < CC; k0 += 32) {
    bf16x8 a[2], b[2];
#pragma unroll
    for (int i = 0; i < 2; ++i) {
      a[i] = *(const bf16x8*)(xh + (size_t)(r0 + i * 16 + lr) * CC + k0 + lg * 8);
      b[i] = *(const bf16x8*)(wqkv + (size_t)(c0 + i * 16 + lr) * CC + k0 + lg * 8);
    }
#pragma unroll
    for (int mi = 0; mi < 2; ++mi)
#pragma unroll
      for (int ni = 0; ni < 2; ++ni)
        acc[mi][ni] = MFMA16(a[mi], b[ni], acc[mi][ni]);
  }

#pragma unroll
  for (int mi = 0; mi < 2; ++mi) {
#pragma unroll
    for (int ni = 0; ni < 2; ++ni) {
      const int col = c0 + ni * 16 + lr;
#pragma unroll
      for (int r = 0; r < 4; ++r) {
        const int m = r0 + mi * 16 + lg * 4 + r;
        float v = acc[mi][ni][r];
        float partner = __shfl_xor(v, 1);
        const int bi = m >> 11, t = m & 2047;
        const int d = col & 63;
        if (col < 768) {  // RoPE for q and k
          const int pi = d >> 1;
          const float c = tc[t * 32 + pi], s = ts[t * 32 + pi];
          v = (d & 1) ? (partner * s + v * c) : (v * c - partner * s);
        }
        if (col < 576) {
          const int h = col >> 6;
          qb[(((size_t)bi * NH + h) * TT + t) * HD + d] = f2bf(v * QSC);
        } else if (col < 768) {
          const int h = (col - 576) >> 6;
          const size_t head = (size_t)bi * NKV + h;
          kst[((head * 32 + (t >> 6)) * 64 + (t & 63)) * 64 + (d ^ ((t & 7) << 3))] = f2bf(v);
        } else {
          const int h = (col - 768) >> 6;
          const size_t head = (size_t)bi * NKV + h;
          vst[((head * 32 + (t >> 6)) * 64 + d) * 64 + ((t & 63) ^ ((d & 7) << 3))] = f2bf(v);
        }
      }
    }
  }
}

// ---------------------------------------------------------------------------
// Flash attention v3: swapped QK^T (mfma(K,Q)) -> lane-local softmax rows.
// grid = (16 pairs, 9, 4), block = 128 (2 waves x 32 q-rows). KVBLK=64,
// double-buffered LDS K/V staging, in-register softmax w/ defer-max,
// cvt_pk + permlane32_swap P->A-fragment conversion.
// ---------------------------------------------------------------------------
__global__ __launch_bounds__(128) void attn_kernel(
    const unsigned short* __restrict__ qb, const unsigned short* __restrict__ kst,
    const unsigned short* __restrict__ vst, unsigned short* __restrict__ yb) {
  const int pair = blockIdx.x, h = blockIdx.y, b = blockIdx.z;
  const int l = threadIdx.x & 63, w = threadIdx.x >> 6;  // w in {0,1}
  const int ln = l & 31, hi = l >> 5;
  const int kvh = h / 3;
  const size_t head = (size_t)b * NKV + kvh;

  const int qtA = 31 - pair, qtB = pair;
  const int ntA = qtA + 1;
  const int nt = ntA + qtB + 1;   // 33 always

  __shared__ unsigned short kls[2][4096];
  __shared__ unsigned short vls[2][4096];

  const unsigned short* qptr = qb + ((size_t)b * NH + h) * TT * HD;

  // Q fragments (B-operand of swapped MFMA): row = lane&31, d = ds*16+hi*8+j
  bf16x8 qA[4], qB[4];
#pragma unroll
  for (int ds = 0; ds < 4; ++ds) {
    qA[ds] = *(const bf16x8*)(qptr + (size_t)(qtA * 64 + w * 32 + ln) * HD + ds * 16 + hi * 8);
    qB[ds] = *(const bf16x8*)(qptr + (size_t)(qtB * 64 + w * 32 + ln) * HD + ds * 16 + hi * 8);
  }

  const char* kgb = (const char*)(kst + head * 32 * 4096);
  const char* vgb = (const char*)(vst + head * 32 * 4096);

  float mi = -1e30f, li = 0.f;
  f32x16 o0, o1;
#pragma unroll
  for (int r = 0; r < 16; ++r) { o0[r] = 0.f; o1[r] = 0.f; }

  // stage tile 0 into buffer 0 (wave w copies bytes [w*4096, w*4096+4096))
  {
#pragma unroll
    for (int i = 0; i < 4; ++i) {
      const int off = w * 4096 + i * 1024;
      gl16(kgb + off + l * 16, (char*)&kls[0][0] + off);
      gl16(vgb + off + l * 16, (char*)&vls[0][0] + off);
    }
  }
  __syncthreads();

  const int swz = (ln & 7) << 4;
  int cur = 0;

  for (int it = 0; it < nt; ++it) {
    const bool segA = it < ntA;
    const int jt = segA ? it : it - ntA;
    const int qt = segA ? qtA : qtB;
    const int qrow = qt * 64 + w * 32 + ln;

    if (it + 1 < nt) {  // stage next tile into other buffer
      const int njt = (it + 1 < ntA) ? it + 1 : it + 1 - ntA;
      const size_t tb = (size_t)njt * 8192;
      char* kl = (char*)&kls[cur ^ 1][0];
      char* vl = (char*)&vls[cur ^ 1][0];
#pragma unroll
      for (int i = 0; i < 4; ++i) {
        const int off = w * 4096 + i * 1024;
        gl16(kgb + tb + off + l * 16, kl + off);
        gl16(vgb + tb + off + l * 16, vl + off);
      }
    }

    const char* kb = (const char*)&kls[cur][0];
    const char* vb = (const char*)&vls[cur][0];

    // QK^T swapped: S^T[k, q] ; lane holds q-row = ln, k = 32t + crow(r,hi)
    f32x16 s0, s1;
#pragma unroll
    for (int r = 0; r < 16; ++r) { s0[r] = 0.f; s1[r] = 0.f; }
    __builtin_amdgcn_s_setprio(1);
#pragma unroll
    for (int ds = 0; ds < 4; ++ds) {
      const bf16x8 qf = segA ? qA[ds] : qB[ds];
      const int cb = (ds * 32 + hi * 16) ^ swz;
      bf16x8 k0 = *(const bf16x8*)(kb + ln * 128 + cb);
      bf16x8 k1 = *(const bf16x8*)(kb + (32 + ln) * 128 + cb);
      s0 = MFMA32(k0, qf, s0);
      s1 = MFMA32(k1, qf, s1);
    }
    __builtin_amdgcn_s_setprio(0);

    if (jt == qt) {  // diagonal tile: causal mask (elementwise)
#pragma unroll
      for (int r = 0; r < 16; ++r) {
        const int kg = jt * 64 + (r & 3) + 8 * (r >> 2) + 4 * hi;
        if (kg > qrow) s0[r] = -1e30f;
        if (kg + 32 > qrow) s1[r] = -1e30f;
      }
    }

    // row max: in-register tree + one cross-half exchange
    float tm[16];
#pragma unroll
    for (int r = 0; r < 16; ++r) tm[r] = fmaxf(s0[r], s1[r]);
#pragma unroll
    for (int st = 8; st >= 1; st >>= 1)
#pragma unroll
      for (int r = 0; r < 8; ++r)
        if (r < st) tm[r] = fmaxf(tm[r], tm[r + st]);
    const float pm = fmaxf(tm[0], __shfl_xor(tm[0], 32));

    // defer-max: only rescale when the running max grows by > 8 (2^8 headroom)
    if (!__all(pm <= mi + 8.0f)) {
      const float mn = fmaxf(mi, pm);
      const float al = exp2f(mi - mn);
      mi = mn;
      li *= al;
#pragma unroll
      for (int r = 0; r < 16; ++r) {
        const float ar = __shfl(al, (r & 3) + 8 * (r >> 2) + 4 * hi);
        o0[r] *= ar;
        o1[r] *= ar;
      }
    }

    // P = exp2(S - mi), row-sum in-register
#pragma unroll
    for (int r = 0; r < 16; ++r) {
      s0[r] = exp2f(s0[r] - mi);
      s1[r] = exp2f(s1[r] - mi);
    }
    float tsum[16];
#pragma unroll
    for (int r = 0; r < 16; ++r) tsum[r] = s0[r] + s1[r];
#pragma unroll
    for (int st = 8; st >= 1; st >>= 1)
#pragma unroll
      for (int r = 0; r < 8; ++r)
        if (r < st) tsum[r] += tsum[r + st];
    li += tsum[0] + __shfl_xor(tsum[0], 32);

    // pack P -> PV A-fragments: 16 cvt_pk + 8 permlane32_swap
    unsigned int pa[4][4];
#pragma unroll
    for (int t = 0; t < 2; ++t) {
#pragma unroll
      for (int m = 0; m < 2; ++m) {
        float p0 = t ? s1[8 * m + 0] : s0[8 * m + 0];
        float p1 = t ? s1[8 * m + 1] : s0[8 * m + 1];
        float p2 = t ? s1[8 * m + 2] : s0[8 * m + 2];
        float p3 = t ? s1[8 * m + 3] : s0[8 * m + 3];
        float p4 = t ? s1[8 * m + 4] : s0[8 * m + 4];
        float p5 = t ? s1[8 * m + 5] : s0[8 * m + 5];
        float p6 = t ? s1[8 * m + 6] : s0[8 * m + 6];
        float p7 = t ? s1[8 * m + 7] : s0[8 * m + 7];
        unsigned int w0, w1, w2, w3;
        asm("v_cvt_pk_bf16_f32 %0, %1, %2" : "=v"(w0) : "v"(p0), "v"(p1));
        asm("v_cvt_pk_bf16_f32 %0, %1, %2" : "=v"(w1) : "v"(p2), "v"(p3));
        asm("v_cvt_pk_bf16_f32 %0, %1, %2" : "=v"(w2) : "v"(p4), "v"(p5));
        asm("v_cvt_pk_bf16_f32 %0, %1, %2" : "=v"(w3) : "v"(p6), "v"(p7));
        asm("v_permlane32_swap_b32 %0, %1" : "+v"(w0), "+v"(w2));
        asm("v_permlane32_swap_b32 %0, %1" : "+v"(w1), "+v"(w3));
        pa[2 * t + m][0] = w0; pa[2 * t + m][1] = w1;
        pa[2 * t + m][2] = w2; pa[2 * t + m][3] = w3;
      }
    }

    // PV: O[q, d] += P[q, k] V[k, d]
    __builtin_amdgcn_s_setprio(1);
#pragma unroll
    for (int ks = 0; ks < 4; ++ks) {
      union { unsigned int u[4]; bf16x8 v; } cvt;
      cvt.u[0] = pa[ks][0]; cvt.u[1] = pa[ks][1];
      cvt.u[2] = pa[ks][2]; cvt.u[3] = pa[ks][3];
      const int cb = (ks * 32 + hi * 16) ^ swz;
      bf16x8 v0 = *(const bf16x8*)(vb + ln * 128 + cb);
      bf16x8 v1 = *(const bf16x8*)(vb + (32 + ln) * 128 + cb);
      o0 = MFMA32(cvt.v, v0, o0);
      o1 = MFMA32(cvt.v, v1, o1);
    }
    __builtin_amdgcn_s_setprio(0);

    if (jt == qt) {  // segment done: normalize + write, reset state
      const float inv = 1.0f / li;
#pragma unroll
      for (int r = 0; r < 16; ++r) {
        const int cr = (r & 3) + 8 * (r >> 2) + 4 * hi;
        const float ir = __shfl(inv, cr);
        const int t = qt * 64 + w * 32 + cr;
        unsigned short* yp = yb + ((size_t)b * TT + t) * CC + h * HD;
        yp[ln] = f2bf(o0[r] * ir);
        yp[32 + ln] = f2bf(o1[r] * ir);
      }
      mi = -1e30f; li = 0.f;
#pragma unroll
      for (int r = 0; r < 16; ++r) { o0[r] = 0.f; o1[r] = 0.f; }
    }

    __syncthreads();
    cur ^= 1;
  }
}

// ---------------------------------------------------------------------------
// GEMM2: y [8192 x 576] @ wo [576 x 576]^T -> out f32
// ---------------------------------------------------------------------------
__global__ __launch_bounds__(256) void gemm_out(
    const unsigned short* __restrict__ yb, const unsigned short* __restrict__ woh,
    float* __restrict__ out) {
  const int l = threadIdx.x & 63, w = threadIdx.x >> 6;
  const int lr = l & 15, lg = l >> 4;
  const int wr = w >> 1, wc = w & 1;
  const int bm = blockIdx.y * 64, bn = blockIdx.x * 64;
  const int r0 = bm + wr * 32, c0 = bn + wc * 32;

  f32x4 acc[2][2] = {};
#pragma unroll 2
  for (int k0 = 0; k0 < CC; k0 += 32) {
    bf16x8 a[2], b[2];
#pragma unroll
    for (int i = 0; i < 2; ++i) {
      a[i] = *(const bf16x8*)(yb + (size_t)(r0 + i * 16 + lr) * CC + k0 + lg * 8);
      b[i] = *(const bf16x8*)(woh + (size_t)(c0 + i * 16 + lr) * CC + k0 + lg * 8);
    }
#pragma unroll
    for (int mi = 0; mi < 2; ++mi)
#pragma unroll
      for (int ni = 0; ni < 2; ++ni)
        acc[mi][ni] = MFMA16(a[mi], b[ni], acc[mi][ni]);
  }
#pragma unroll
  for (int mi = 0; mi < 2; ++mi)
#pragma unroll
    for (int ni = 0; ni < 2; ++ni) {
      const int col = c0 + ni * 16 + lr;
#pragma unroll
      for (int r = 0; r < 4; ++r) {
        const int m = r0 + mi * 16 + lg * 4 + r;
        out[(size_t)m * CC + col] = acc[mi][ni][r];
      }
    }
}

// ---------------------------------------------------------------------------
extern "C" void kernel_launch(void* const* d_in, const int* in_sizes, int n_in,
                              void* d_out, int out_size, void* d_ws, size_t ws_size,
                              hipStream_t stream) {
  const float* x = (const float*)d_in[0];
  const float* wq = (const float*)d_in[1];
  const float* wk = (const float*)d_in[2];
  const float* wv = (const float*)d_in[3];
  const float* wo = (const float*)d_in[4];
  float* out = (float*)d_out;

  char* ws = (char*)d_ws;
  unsigned short* xh = (unsigned short*)ws;    ws += (size_t)MM * CC * 2;
  unsigned short* wqkv = (unsigned short*)ws;  ws += (size_t)NQKV * CC * 2;
  unsigned short* woh = (unsigned short*)ws;   ws += (size_t)CC * CC * 2;
  float* tc = (float*)ws;                      ws += (size_t)TT * 32 * 4;
  float* tsn = (float*)ws;                     ws += (size_t)TT * 32 * 4;
  unsigned short* qb = (unsigned short*)ws;    ws += (size_t)BB * NH * TT * HD * 2;
  unsigned short* kst = (unsigned short*)ws;   ws += (size_t)BB * NKV * TT * HD * 2;
  unsigned short* vst = (unsigned short*)ws;   ws += (size_t)BB * NKV * HD * TT * 2;
  unsigned short* yb = (unsigned short*)ws;    ws += (size_t)MM * CC * 2;

  prep_kernel<<<dim3(2048), dim3(256), 0, stream>>>(x, wq, wk, wv, wo, xh, wqkv, woh, tc, tsn);
  gemm_qkv<<<dim3(NQKV / 64, MM / 64), dim3(256), 0, stream>>>(xh, wqkv, tc, tsn, qb, kst, vst);
  attn_kernel<<<dim3(16, NH, BB), dim3(128), 0, stream>>>(qb, kst, vst, yb);
  gemm_out<<<dim3(CC / 64, MM / 64), dim3(256), 0, stream>>>(yb, woh, out);
}